// Round 8
// baseline (206.479 us; speedup 1.0000x reference)
//
#include <hip/hip_runtime.h>

// B=16, H=W=64, C=80; tables (127,80) -> reference resize is a no-op.
// Output (B,N,N) fp32 = 1.074 GB: HBM write-stream problem, floor ~165 us.
//
// v7: persistent-ish blocks. One block per (b,hh) row: stage ALL pw (127
// padded rows) + all 64 q rows once, one barrier, then each wave runs its
// 16 tokens {dot -> shuffle -> 16 nt stores} with NO further sync. Stores
// are fire-and-forget: the wave computes token k+1 while token k's stores
// drain; vmcnt(0) happens once per block (1 MB) instead of per 256 KB.
#define HH 64
#define WW 64
#define CC 80
#define NN (HH * WW)
#define NPW 127        // all pw rows
#define SP  84         // padded LDS stride: 16B-aligned rows, bank-balanced

typedef float vf4 __attribute__((ext_vector_type(4)));

__global__ __launch_bounds__(256, 2) void relpos_fused_v7(
    const float* __restrict__ q,    // (B, N, C)
    const float* __restrict__ ph,   // (127, 80)
    const float* __restrict__ pw,   // (127, 80)
    float* __restrict__ out)        // (B, N, N)
{
    __shared__ float sh_q [64 * CC];     // 20.0 KB (all 64 tokens of the row)
    __shared__ float sh_pw[NPW * SP];    // 42.7 KB -> 61.7 KB total, 2 blk/CU

    const int blk = blockIdx.x;          // b*64 + hh
    const int hh  = blk & 63;
    const int b   = blk >> 6;
    const int t   = threadIdx.x;
    const int j   = t & 63;
    const int w   = t >> 6;

    // ---- Phase 1: stage 64 q rows + full pw table (coalesced) ----
    const vf4* qin4 = reinterpret_cast<const vf4*>(
        q + ((size_t)b * NN + hh * 64) * CC);            // 1280 vf4
    vf4* shq4 = reinterpret_cast<vf4*>(sh_q);
    #pragma unroll
    for (int p = t; p < 64 * CC / 4; p += 256) shq4[p] = qin4[p];

    const vf4* pwsrc = reinterpret_cast<const vf4*>(pw); // 2540 vf4
    vf4* shpw4 = reinterpret_cast<vf4*>(sh_pw);
    for (int p = t; p < NPW * (CC / 4); p += 256) {
        const int r  = p / 20;
        const int c4 = p % 20;
        shpw4[r * (SP / 4) + c4] = pwsrc[p];
    }
    __syncthreads();                     // the ONLY barrier

    // Hoist this lane's ph row (depends on hh, j only) into 20 VGPR vf4s;
    // reused across all 16 tokens.
    vf4 hv[20];
    const vf4* phrow = reinterpret_cast<const vf4*>(
        ph + (size_t)(hh + 63 - j) * CC);
    #pragma unroll
    for (int c = 0; c < 20; ++c) hv[c] = phrow[c];

    vf4* outbase = reinterpret_cast<vf4*>(
        out + ((size_t)b * NN + hh * 64) * NN);
    const int rwlane = 4 * (j & 15);
    const int rhbase = j >> 4;

    // ---- Per-wave token loop: tokens g = 4k + w ----
    for (int k = 0; k < 16; ++k) {
        const int g = 4 * k + w;
        const float* qrow = &sh_q[g * CC];               // wave-broadcast
        const float* wrow = &sh_pw[(size_t)(g + 63 - j) * SP];  // gather

        float acch = 0.f, accw = 0.f;
        #pragma unroll
        for (int c = 0; c < 20; ++c) {
            vf4 qv = *reinterpret_cast<const vf4*>(qrow + 4 * c);
            vf4 wv = *reinterpret_cast<const vf4*>(wrow + 4 * c);
            acch += qv.x * hv[c].x + qv.y * hv[c].y
                  + qv.z * hv[c].z + qv.w * hv[c].w;
            accw += qv.x * wv.x + qv.y * wv.y + qv.z * wv.z + qv.w * wv.w;
        }

        // Cross-lane redistribution (mapping verified in v6):
        // out f4 p = it*64 + j: rh idx = it*4 + (j>>4), rw floats 4(j&15)+e.
        const float w0 = __shfl(accw, rwlane + 0);
        const float w1 = __shfl(accw, rwlane + 1);
        const float w2 = __shfl(accw, rwlane + 2);
        const float w3 = __shfl(accw, rwlane + 3);
        float rh[16];
        #pragma unroll
        for (int it = 0; it < 16; ++it)
            rh[it] = __shfl(acch, it * 4 + rhbase);

        vf4* o4 = outbase + (size_t)g * 1024;
        #pragma unroll
        for (int it = 0; it < 16; ++it) {
            vf4 o;
            o.x = rh[it] + w0; o.y = rh[it] + w1;
            o.z = rh[it] + w2; o.w = rh[it] + w3;
            __builtin_nontemporal_store(o, &o4[it * 64 + j]);
        }
    }
}

extern "C" void kernel_launch(void* const* d_in, const int* in_sizes, int n_in,
                              void* d_out, int out_size, void* d_ws, size_t ws_size,
                              hipStream_t stream) {
    const float* q  = (const float*)d_in[0];
    const float* ph = (const float*)d_in[1];
    const float* pw = (const float*)d_in[2];
    float* out = (float*)d_out;

    const int B = in_sizes[0] / (NN * CC);        // 16
    dim3 grid(B * HH);                             // 1024 blocks, one per row
    relpos_fused_v7<<<grid, 256, 0, stream>>>(q, ph, pw, out);
}